// Round 2
// baseline (171.124 us; speedup 1.0000x reference)
//
#include <hip/hip_runtime.h>
#include <math.h>

// D3 constants
#define K1C 16.0f
#define K2C (4.0f / 3.0f)
#define K3C 4.0f
#define A1C 0.4f
#define A2C 5.0f
#define S6C 1.0f
#define S8C 0.78f
#define CN_CUT 25.0f
#define DISP_CUT 50.0f
#define MAXZ 95
#define NREF 5
#define TPAD 28   // padded C6 panel stride (floats), 16B-aligned rows of 25+3

typedef float f4 __attribute__((ext_vector_type(4)));

// ---------------- Kernel 0: pack per-atom records + repack C6 table ----------------
// atomrec[a] = {x, y, z, rcov[za]} {r4r2[za], bits(za), 0, 0}   (32B, one cache line)
// tabp[p*28 + k] = c6tab[p*25 + k]  (16B-aligned panels -> 7 dwordx4 loads)
__global__ void pack_kernel(const float* __restrict__ pos,
                            const int* __restrict__ numbers,
                            const float* __restrict__ rcov,
                            const float* __restrict__ r4r2,
                            const float* __restrict__ c6tab,
                            float* __restrict__ atomrec,
                            float* __restrict__ tabp,
                            int n_atoms) {
    int t = blockIdx.x * blockDim.x + threadIdx.x;
    int stride = gridDim.x * blockDim.x;
    const int ntab = MAXZ * MAXZ;
    for (int p = t; p < ntab; p += stride) {
        const float* src = c6tab + (size_t)p * 25;
        float* dst = tabp + (size_t)p * TPAD;
#pragma unroll
        for (int k = 0; k < 25; ++k) dst[k] = src[k];
        dst[25] = 0.f; dst[26] = 0.f; dst[27] = 0.f;
    }
    for (int a = t; a < n_atoms; a += stride) {
        int z = numbers[a];
        f4* rec = (f4*)(atomrec + (size_t)a * 8);
        f4 r0 = { pos[3 * a + 0], pos[3 * a + 1], pos[3 * a + 2], rcov[z] };
        f4 r1 = { r4r2[z], __int_as_float(z), 0.f, 0.f };
        rec[0] = r0;
        rec[1] = r1;
    }
}

// ---------------- Kernel 1: fused CN scatter-add + edge precompute ----------------
// edgerec[e] = {d, qq, bits(zi*95+zj), 0}
__global__ void cn_pre_kernel(const float* __restrict__ atomrec,
                              const int* __restrict__ ei,
                              const int* __restrict__ ej,
                              float* __restrict__ cn,
                              f4* __restrict__ edgerec,
                              int n_edges) {
    int stride = gridDim.x * blockDim.x;
    for (int e = blockIdx.x * blockDim.x + threadIdx.x; e < n_edges; e += stride) {
        int i = ei[e];
        int j = ej[e];
        const f4* Ai = (const f4*)(atomrec) + 2 * (size_t)i;
        const f4* Aj = (const f4*)(atomrec) + 2 * (size_t)j;
        f4 a0 = Ai[0], a1 = Ai[1];
        f4 b0 = Aj[0], b1 = Aj[1];
        float dx = b0.x - a0.x;
        float dy = b0.y - a0.y;
        float dz = b0.z - a0.z;
        float d = sqrtf(dx * dx + dy * dy + dz * dz + 1e-20f);
        if (d < CN_CUT) {
            float rr = a0.w + b0.w;
            float x = K1C * (K2C * rr / d - 1.0f);
            float s = 1.0f / (1.0f + expf(-x));
            atomicAdd(&cn[i], s);
        }
        int zi = __float_as_int(a1.y);
        int zj = __float_as_int(b1.y);
        float qq = 3.0f * a1.x * b1.x;
        f4 rec = { d, qq, __int_as_float(zi * MAXZ + zj), 0.f };
        edgerec[e] = rec;
    }
}

// ---------------- Kernel 2: per-atom CN-Gaussian weights (padded to 8 floats) ----------------
__global__ void weights_kernel(const float* __restrict__ cn,
                               const int* __restrict__ numbers,
                               const float* __restrict__ cn_ref,
                               float* __restrict__ W,
                               int n_atoms) {
    int stride = gridDim.x * blockDim.x;
    for (int a = blockIdx.x * blockDim.x + threadIdx.x; a < n_atoms; a += stride) {
        int z = numbers[a];
        float c = cn[a];
        float gw[NREF];
        float norm = 0.0f;
        float best = -INFINITY;
        int bi = 0;
#pragma unroll
        for (int m = 0; m < NREF; ++m) {
            float r = cn_ref[z * NREF + m];
            bool valid = (r >= 0.0f);
            float t = c - r;
            float g = valid ? expf(-K3C * t * t) : 0.0f;
            gw[m] = g;
            norm += g;
            if (valid && r > best) { best = r; bi = m; }  // first occurrence of max
        }
        float out[NREF];
        if (norm > 1e-30f) {
            float inv = 1.0f / norm;
#pragma unroll
            for (int m = 0; m < NREF; ++m) out[m] = gw[m] * inv;
        } else {
#pragma unroll
            for (int m = 0; m < NREF; ++m) out[m] = (m == bi) ? 1.0f : 0.0f;
        }
        f4* Wv = (f4*)(W + (size_t)a * 8);
        f4 w0 = { out[0], out[1], out[2], out[3] };
        f4 w1 = { out[4], 0.f, 0.f, 0.f };
        Wv[0] = w0;
        Wv[1] = w1;
    }
}

// ---------------- Kernel 3: pair dispersion energy + reduction ----------------
__global__ void energy_kernel(const int* __restrict__ ei,
                              const int* __restrict__ ej,
                              const f4* __restrict__ edgerec,
                              const f4* __restrict__ Wv,
                              const float* __restrict__ tabp,
                              double* __restrict__ acc,
                              int n_edges) {
    double local = 0.0;
    int stride = gridDim.x * blockDim.x;
    for (int e = blockIdx.x * blockDim.x + threadIdx.x; e < n_edges; e += stride) {
        f4 rec = edgerec[e];
        float d = rec.x;
        if (d < DISP_CUT) {
            int i = ei[e];
            int j = ej[e];
            f4 wi0 = Wv[2 * (size_t)i], wi1 = Wv[2 * (size_t)i + 1];
            f4 wj0 = Wv[2 * (size_t)j], wj1 = Wv[2 * (size_t)j + 1];
            int pidx = __float_as_int(rec.z);
            const f4* T = (const f4*)(tabp + (size_t)pidx * TPAD);
            float tt[TPAD];
            f4* ttv = (f4*)tt;
#pragma unroll
            for (int k = 0; k < 7; ++k) ttv[k] = T[k];
            float wiv[NREF] = { wi0.x, wi0.y, wi0.z, wi0.w, wi1.x };
            float wjv[NREF] = { wj0.x, wj0.y, wj0.z, wj0.w, wj1.x };
            float c6 = 0.0f;
#pragma unroll
            for (int a = 0; a < NREF; ++a) {
                float s = 0.0f;
#pragma unroll
                for (int b = 0; b < NREF; ++b) s += wjv[b] * tt[a * NREF + b];
                c6 += wiv[a] * s;
            }
            float qq = rec.y;
            float c8 = c6 * qq;
            float f = A1C * sqrtf(qq) + A2C;
            float f2 = f * f;
            float f6 = f2 * f2 * f2;
            float f8 = f6 * f2;
            float d2 = d * d;
            float d6 = d2 * d2 * d2;
            float d8 = d6 * d2;
            float e_pair = -(S6C * c6 / (d6 + f6) + S8C * c8 / (d8 + f8));
            local += 0.5 * (double)e_pair;
        }
    }
#pragma unroll
    for (int off = 32; off > 0; off >>= 1) local += __shfl_down(local, off, 64);
    __shared__ double wsum[8];
    int lane = threadIdx.x & 63;
    int wave = threadIdx.x >> 6;
    if (lane == 0) wsum[wave] = local;
    __syncthreads();
    if (threadIdx.x == 0) {
        double b = 0.0;
        int nwaves = (blockDim.x + 63) >> 6;
        for (int w = 0; w < nwaves; ++w) b += wsum[w];
        atomicAdd(acc, b);
    }
}

// ---------------- Fallback kernels (small-ws path, round-1 structure) ----------------
__global__ void cn_kernel_old(const float* __restrict__ pos,
                              const int* __restrict__ numbers,
                              const int* __restrict__ ei,
                              const int* __restrict__ ej,
                              const float* __restrict__ rcov,
                              float* __restrict__ cn,
                              int n_edges) {
    int stride = gridDim.x * blockDim.x;
    for (int e = blockIdx.x * blockDim.x + threadIdx.x; e < n_edges; e += stride) {
        int i = ei[e];
        int j = ej[e];
        float dx = pos[3 * j + 0] - pos[3 * i + 0];
        float dy = pos[3 * j + 1] - pos[3 * i + 1];
        float dz = pos[3 * j + 2] - pos[3 * i + 2];
        float d = sqrtf(dx * dx + dy * dy + dz * dz + 1e-20f);
        if (d < CN_CUT) {
            float rr = rcov[numbers[i]] + rcov[numbers[j]];
            float x = K1C * (K2C * rr / d - 1.0f);
            atomicAdd(&cn[i], 1.0f / (1.0f + expf(-x)));
        }
    }
}

__global__ void energy_kernel_old(const float* __restrict__ pos,
                                  const int* __restrict__ numbers,
                                  const int* __restrict__ ei,
                                  const int* __restrict__ ej,
                                  const float* __restrict__ r4r2,
                                  const float* __restrict__ c6tab,
                                  const f4* __restrict__ Wv,
                                  double* __restrict__ acc,
                                  int n_edges) {
    double local = 0.0;
    int stride = gridDim.x * blockDim.x;
    for (int e = blockIdx.x * blockDim.x + threadIdx.x; e < n_edges; e += stride) {
        int i = ei[e];
        int j = ej[e];
        float dx = pos[3 * j + 0] - pos[3 * i + 0];
        float dy = pos[3 * j + 1] - pos[3 * i + 1];
        float dz = pos[3 * j + 2] - pos[3 * i + 2];
        float d = sqrtf(dx * dx + dy * dy + dz * dz + 1e-20f);
        if (d < DISP_CUT) {
            int zi = numbers[i];
            int zj = numbers[j];
            const float* __restrict__ T = c6tab + ((size_t)(zi * MAXZ + zj)) * 25;
            f4 wi0 = Wv[2 * (size_t)i], wi1 = Wv[2 * (size_t)i + 1];
            f4 wj0 = Wv[2 * (size_t)j], wj1 = Wv[2 * (size_t)j + 1];
            float wiv[NREF] = { wi0.x, wi0.y, wi0.z, wi0.w, wi1.x };
            float wjv[NREF] = { wj0.x, wj0.y, wj0.z, wj0.w, wj1.x };
            float c6 = 0.0f;
#pragma unroll
            for (int a = 0; a < NREF; ++a) {
                float s = 0.0f;
#pragma unroll
                for (int b = 0; b < NREF; ++b) s += wjv[b] * T[a * NREF + b];
                c6 += wiv[a] * s;
            }
            float qq = 3.0f * r4r2[zi] * r4r2[zj];
            float c8 = c6 * qq;
            float f = A1C * sqrtf(qq) + A2C;
            float f2 = f * f;
            float f6 = f2 * f2 * f2;
            float f8 = f6 * f2;
            float d2 = d * d;
            float d6 = d2 * d2 * d2;
            float d8 = d6 * d2;
            float e_pair = -(S6C * c6 / (d6 + f6) + S8C * c8 / (d8 + f8));
            local += 0.5 * (double)e_pair;
        }
    }
#pragma unroll
    for (int off = 32; off > 0; off >>= 1) local += __shfl_down(local, off, 64);
    __shared__ double wsum[8];
    int lane = threadIdx.x & 63;
    int wave = threadIdx.x >> 6;
    if (lane == 0) wsum[wave] = local;
    __syncthreads();
    if (threadIdx.x == 0) {
        double b = 0.0;
        int nwaves = (blockDim.x + 63) >> 6;
        for (int w = 0; w < nwaves; ++w) b += wsum[w];
        atomicAdd(acc, b);
    }
}

// ---------------- Kernel 4: finalize ----------------
__global__ void finalize_kernel(const double* __restrict__ acc, float* __restrict__ out) {
    out[0] = (float)acc[0];
}

static inline size_t align16(size_t x) { return (x + 15) & ~(size_t)15; }

extern "C" void kernel_launch(void* const* d_in, const int* in_sizes, int n_in,
                              void* d_out, int out_size, void* d_ws, size_t ws_size,
                              hipStream_t stream) {
    const float* pos     = (const float*)d_in[0];
    const int*   numbers = (const int*)d_in[1];
    const int*   ei      = (const int*)d_in[2];
    const int*   ej      = (const int*)d_in[3];
    const float* rcov    = (const float*)d_in[4];
    const float* r4r2    = (const float*)d_in[5];
    const float* c6tab   = (const float*)d_in[6];
    const float* cn_ref  = (const float*)d_in[7];

    int n_atoms = in_sizes[1];
    int n_edges = in_sizes[2];

    char* ws = (char*)d_ws;
    size_t off = 0;
    float* cn = (float*)(ws + off);       off += align16((size_t)n_atoms * 4);
    double* acc = (double*)(ws + off);    size_t zero_bytes = off + 16; off += 16;
    float* W = (float*)(ws + off);        off += (size_t)n_atoms * 32;
    size_t small_needed = off;
    float* atomrec = (float*)(ws + off);  off += (size_t)n_atoms * 32;
    float* tabp = (float*)(ws + off);     off += align16((size_t)MAXZ * MAXZ * TPAD * 4);
    f4* edgerec = (f4*)(ws + off);        off += (size_t)n_edges * 16;
    size_t full_needed = off;

    hipMemsetAsync(d_ws, 0, zero_bytes, stream);

    const int block = 256;
    int egrid = (n_edges + block - 1) / block;
    int agrid = (n_atoms + block - 1) / block;
    int pgrid = ((MAXZ * MAXZ > n_atoms ? MAXZ * MAXZ : n_atoms) + block - 1) / block;

    if (ws_size >= full_needed) {
        pack_kernel<<<pgrid, block, 0, stream>>>(pos, numbers, rcov, r4r2, c6tab,
                                                 atomrec, tabp, n_atoms);
        cn_pre_kernel<<<egrid, block, 0, stream>>>(atomrec, ei, ej, cn, edgerec, n_edges);
        weights_kernel<<<agrid, block, 0, stream>>>(cn, numbers, cn_ref, W, n_atoms);
        energy_kernel<<<egrid, block, 0, stream>>>(ei, ej, edgerec, (const f4*)W, tabp,
                                                   acc, n_edges);
    } else if (ws_size >= small_needed) {
        cn_kernel_old<<<egrid, block, 0, stream>>>(pos, numbers, ei, ej, rcov, cn, n_edges);
        weights_kernel<<<agrid, block, 0, stream>>>(cn, numbers, cn_ref, W, n_atoms);
        energy_kernel_old<<<egrid, block, 0, stream>>>(pos, numbers, ei, ej, r4r2, c6tab,
                                                       (const f4*)W, acc, n_edges);
    }
    finalize_kernel<<<1, 1, 0, stream>>>(acc, (float*)d_out);
}

// Round 3
// 120.342 us; speedup vs baseline: 1.4220x; 1.4220x over previous
//
#include <hip/hip_runtime.h>
#include <math.h>

// D3 constants
#define K1C 16.0f
#define K2C (4.0f / 3.0f)
#define K3C 4.0f
#define A1C 0.4f
#define A2C 5.0f
#define S6C 1.0f
#define S8C 0.78f
#define CN_CUT 25.0f
#define DISP_CUT 50.0f
#define MAXZ 95
#define NREF 5
#define TPAD 28   // padded C6 panel stride (floats)
#define IPT 4     // edges per thread (blocked)

typedef float f4 __attribute__((ext_vector_type(4)));

// ---------------- Kernel 0: pack per-atom records + repack C6 table ----------------
__global__ void pack_kernel(const float* __restrict__ pos,
                            const int* __restrict__ numbers,
                            const float* __restrict__ rcov,
                            const float* __restrict__ r4r2,
                            const float* __restrict__ c6tab,
                            float* __restrict__ atomrec,
                            float* __restrict__ tabp,
                            int n_atoms) {
    int t = blockIdx.x * blockDim.x + threadIdx.x;
    int stride = gridDim.x * blockDim.x;
    const int ntab = MAXZ * MAXZ;
    for (int p = t; p < ntab; p += stride) {
        const float* src = c6tab + (size_t)p * 25;
        float* dst = tabp + (size_t)p * TPAD;
#pragma unroll
        for (int k = 0; k < 25; ++k) dst[k] = src[k];
        dst[25] = 0.f; dst[26] = 0.f; dst[27] = 0.f;
    }
    for (int a = t; a < n_atoms; a += stride) {
        int z = numbers[a];
        f4* rec = (f4*)(atomrec + (size_t)a * 8);
        f4 r0 = { pos[3 * a + 0], pos[3 * a + 1], pos[3 * a + 2], rcov[z] };
        f4 r1 = { r4r2[z], __uint_as_float((unsigned)z), 0.f, 0.f };
        rec[0] = r0;
        rec[1] = r1;
    }
}

// ---------------- Kernel 1: fused CN scatter-add + edge record precompute ----------------
// edgerec[e] = {d, qq, bits(i | j<<16), bits(pidx)}
__global__ void cn_pre_kernel(const float* __restrict__ atomrec,
                              const int* __restrict__ ei,
                              const int* __restrict__ ej,
                              float* __restrict__ cn,
                              f4* __restrict__ edgerec,
                              int n_edges) {
    int t = blockIdx.x * blockDim.x + threadIdx.x;
    int stride = gridDim.x * blockDim.x;
    for (int base = t * IPT; base < n_edges; base += stride * IPT) {
        if (base + IPT <= n_edges) {
            int4 i4 = *(const int4*)(ei + base);
            int4 j4 = *(const int4*)(ej + base);
            int ii[IPT] = { i4.x, i4.y, i4.z, i4.w };
            int jj[IPT] = { j4.x, j4.y, j4.z, j4.w };
            f4 a0[IPT], a1[IPT], b0[IPT], b1[IPT];
#pragma unroll
            for (int s = 0; s < IPT; ++s) {
                const f4* Ai = (const f4*)atomrec + 2 * (size_t)ii[s];
                const f4* Aj = (const f4*)atomrec + 2 * (size_t)jj[s];
                a0[s] = Ai[0]; a1[s] = Ai[1];
                b0[s] = Aj[0]; b1[s] = Aj[1];
            }
#pragma unroll
            for (int s = 0; s < IPT; ++s) {
                float dx = b0[s].x - a0[s].x;
                float dy = b0[s].y - a0[s].y;
                float dz = b0[s].z - a0[s].z;
                float d = sqrtf(dx * dx + dy * dy + dz * dz + 1e-20f);
                if (d < CN_CUT) {
                    float rr = a0[s].w + b0[s].w;
                    float x = K1C * (K2C * rr / d - 1.0f);
                    float sg = 1.0f / (1.0f + expf(-x));
                    atomicAdd(&cn[ii[s]], sg);
                }
                int zi = (int)__float_as_uint(a1[s].y);
                int zj = (int)__float_as_uint(b1[s].y);
                float qq = 3.0f * a1[s].x * b1[s].x;
                unsigned ijpack = (unsigned)ii[s] | ((unsigned)jj[s] << 16);
                f4 rec = { d, qq, __uint_as_float(ijpack),
                           __uint_as_float((unsigned)(zi * MAXZ + zj)) };
                edgerec[base + s] = rec;
            }
        } else {
            for (int e = base; e < n_edges; ++e) {
                int i = ei[e], j = ej[e];
                const f4* Ai = (const f4*)atomrec + 2 * (size_t)i;
                const f4* Aj = (const f4*)atomrec + 2 * (size_t)j;
                f4 a0 = Ai[0], a1 = Ai[1], b0 = Aj[0], b1 = Aj[1];
                float dx = b0.x - a0.x, dy = b0.y - a0.y, dz = b0.z - a0.z;
                float d = sqrtf(dx * dx + dy * dy + dz * dz + 1e-20f);
                if (d < CN_CUT) {
                    float rr = a0.w + b0.w;
                    float x = K1C * (K2C * rr / d - 1.0f);
                    atomicAdd(&cn[i], 1.0f / (1.0f + expf(-x)));
                }
                int zi = (int)__float_as_uint(a1.y);
                int zj = (int)__float_as_uint(b1.y);
                float qq = 3.0f * a1.x * b1.x;
                unsigned ijpack = (unsigned)i | ((unsigned)j << 16);
                f4 rec = { d, qq, __uint_as_float(ijpack),
                           __uint_as_float((unsigned)(zi * MAXZ + zj)) };
                edgerec[e] = rec;
            }
        }
    }
}

// ---------------- Kernel 2: per-atom CN-Gaussian weights (padded to 8 floats) ----------------
__global__ void weights_kernel(const float* __restrict__ cn,
                               const int* __restrict__ numbers,
                               const float* __restrict__ cn_ref,
                               float* __restrict__ W,
                               int n_atoms) {
    int stride = gridDim.x * blockDim.x;
    for (int a = blockIdx.x * blockDim.x + threadIdx.x; a < n_atoms; a += stride) {
        int z = numbers[a];
        float c = cn[a];
        float gw[NREF];
        float norm = 0.0f;
        float best = -INFINITY;
        int bi = 0;
#pragma unroll
        for (int m = 0; m < NREF; ++m) {
            float r = cn_ref[z * NREF + m];
            bool valid = (r >= 0.0f);
            float tt = c - r;
            float g = valid ? expf(-K3C * tt * tt) : 0.0f;
            gw[m] = g;
            norm += g;
            if (valid && r > best) { best = r; bi = m; }
        }
        float out[NREF];
        if (norm > 1e-30f) {
            float inv = 1.0f / norm;
#pragma unroll
            for (int m = 0; m < NREF; ++m) out[m] = gw[m] * inv;
        } else {
#pragma unroll
            for (int m = 0; m < NREF; ++m) out[m] = (m == bi) ? 1.0f : 0.0f;
        }
        f4* Wv = (f4*)(W + (size_t)a * 8);
        f4 w0 = { out[0], out[1], out[2], out[3] };
        f4 w1 = { out[4], 0.f, 0.f, 0.f };
        Wv[0] = w0;
        Wv[1] = w1;
    }
}

// ---------------- Kernel 3: batched pair energy + reduction ----------------
__device__ __forceinline__ float edge_energy(f4 rec, const f4* __restrict__ Wv,
                                             const float* __restrict__ tabp) {
    unsigned ij = __float_as_uint(rec.z);
    int i = (int)(ij & 0xFFFFu);
    int j = (int)(ij >> 16);
    int pidx = (int)__float_as_uint(rec.w);
    f4 wi0 = Wv[2 * (size_t)i], wi1 = Wv[2 * (size_t)i + 1];
    f4 wj0 = Wv[2 * (size_t)j], wj1 = Wv[2 * (size_t)j + 1];
    const f4* T = (const f4*)(tabp + (size_t)pidx * TPAD);
    float tt[TPAD];
    f4* ttv = (f4*)tt;
#pragma unroll
    for (int k = 0; k < 7; ++k) ttv[k] = T[k];
    float wiv[NREF] = { wi0.x, wi0.y, wi0.z, wi0.w, wi1.x };
    float wjv[NREF] = { wj0.x, wj0.y, wj0.z, wj0.w, wj1.x };
    float c6 = 0.0f;
#pragma unroll
    for (int a = 0; a < NREF; ++a) {
        float s = 0.0f;
#pragma unroll
        for (int b = 0; b < NREF; ++b) s += wjv[b] * tt[a * NREF + b];
        c6 += wiv[a] * s;
    }
    float d = rec.x;
    float qq = rec.y;
    float c8 = c6 * qq;
    float f = A1C * sqrtf(qq) + A2C;
    float f2 = f * f;
    float f6 = f2 * f2 * f2;
    float f8 = f6 * f2;
    float d2 = d * d;
    float d6 = d2 * d2 * d2;
    float d8 = d6 * d2;
    return -(S6C * c6 / (d6 + f6) + S8C * c8 / (d8 + f8));
}

__global__ void energy_kernel(const f4* __restrict__ edgerec,
                              const f4* __restrict__ Wv,
                              const float* __restrict__ tabp,
                              double* __restrict__ acc,
                              int n_edges) {
    double local = 0.0;
    int t = blockIdx.x * blockDim.x + threadIdx.x;
    int stride = gridDim.x * blockDim.x;
    for (int base = t * IPT; base < n_edges; base += stride * IPT) {
        if (base + IPT <= n_edges) {
            f4 rec[IPT];
#pragma unroll
            for (int s = 0; s < IPT; ++s) rec[s] = edgerec[base + s];
#pragma unroll
            for (int s = 0; s < IPT; ++s) {
                if (rec[s].x < DISP_CUT) {
                    local += 0.5 * (double)edge_energy(rec[s], Wv, tabp);
                }
            }
        } else {
            for (int e = base; e < n_edges; ++e) {
                f4 rec = edgerec[e];
                if (rec.x < DISP_CUT) {
                    local += 0.5 * (double)edge_energy(rec, Wv, tabp);
                }
            }
        }
    }
#pragma unroll
    for (int off = 32; off > 0; off >>= 1) local += __shfl_down(local, off, 64);
    __shared__ double wsum[8];
    int lane = threadIdx.x & 63;
    int wave = threadIdx.x >> 6;
    if (lane == 0) wsum[wave] = local;
    __syncthreads();
    if (threadIdx.x == 0) {
        double b = 0.0;
        int nwaves = (blockDim.x + 63) >> 6;
        for (int w = 0; w < nwaves; ++w) b += wsum[w];
        atomicAdd(acc, b);
    }
}

// ---------------- Fallback kernels (small-ws / large-atom-count path) ----------------
__global__ void cn_kernel_old(const float* __restrict__ pos,
                              const int* __restrict__ numbers,
                              const int* __restrict__ ei,
                              const int* __restrict__ ej,
                              const float* __restrict__ rcov,
                              float* __restrict__ cn,
                              int n_edges) {
    int stride = gridDim.x * blockDim.x;
    for (int e = blockIdx.x * blockDim.x + threadIdx.x; e < n_edges; e += stride) {
        int i = ei[e];
        int j = ej[e];
        float dx = pos[3 * j + 0] - pos[3 * i + 0];
        float dy = pos[3 * j + 1] - pos[3 * i + 1];
        float dz = pos[3 * j + 2] - pos[3 * i + 2];
        float d = sqrtf(dx * dx + dy * dy + dz * dz + 1e-20f);
        if (d < CN_CUT) {
            float rr = rcov[numbers[i]] + rcov[numbers[j]];
            float x = K1C * (K2C * rr / d - 1.0f);
            atomicAdd(&cn[i], 1.0f / (1.0f + expf(-x)));
        }
    }
}

__global__ void energy_kernel_old(const float* __restrict__ pos,
                                  const int* __restrict__ numbers,
                                  const int* __restrict__ ei,
                                  const int* __restrict__ ej,
                                  const float* __restrict__ r4r2,
                                  const float* __restrict__ c6tab,
                                  const f4* __restrict__ Wv,
                                  double* __restrict__ acc,
                                  int n_edges) {
    double local = 0.0;
    int stride = gridDim.x * blockDim.x;
    for (int e = blockIdx.x * blockDim.x + threadIdx.x; e < n_edges; e += stride) {
        int i = ei[e];
        int j = ej[e];
        float dx = pos[3 * j + 0] - pos[3 * i + 0];
        float dy = pos[3 * j + 1] - pos[3 * i + 1];
        float dz = pos[3 * j + 2] - pos[3 * i + 2];
        float d = sqrtf(dx * dx + dy * dy + dz * dz + 1e-20f);
        if (d < DISP_CUT) {
            int zi = numbers[i];
            int zj = numbers[j];
            const float* __restrict__ T = c6tab + ((size_t)(zi * MAXZ + zj)) * 25;
            f4 wi0 = Wv[2 * (size_t)i], wi1 = Wv[2 * (size_t)i + 1];
            f4 wj0 = Wv[2 * (size_t)j], wj1 = Wv[2 * (size_t)j + 1];
            float wiv[NREF] = { wi0.x, wi0.y, wi0.z, wi0.w, wi1.x };
            float wjv[NREF] = { wj0.x, wj0.y, wj0.z, wj0.w, wj1.x };
            float c6 = 0.0f;
#pragma unroll
            for (int a = 0; a < NREF; ++a) {
                float s = 0.0f;
#pragma unroll
                for (int b = 0; b < NREF; ++b) s += wjv[b] * T[a * NREF + b];
                c6 += wiv[a] * s;
            }
            float qq = 3.0f * r4r2[zi] * r4r2[zj];
            float c8 = c6 * qq;
            float f = A1C * sqrtf(qq) + A2C;
            float f2 = f * f;
            float f6 = f2 * f2 * f2;
            float f8 = f6 * f2;
            float d2 = d * d;
            float d6 = d2 * d2 * d2;
            float d8 = d6 * d2;
            float e_pair = -(S6C * c6 / (d6 + f6) + S8C * c8 / (d8 + f8));
            local += 0.5 * (double)e_pair;
        }
    }
#pragma unroll
    for (int off = 32; off > 0; off >>= 1) local += __shfl_down(local, off, 64);
    __shared__ double wsum[8];
    int lane = threadIdx.x & 63;
    int wave = threadIdx.x >> 6;
    if (lane == 0) wsum[wave] = local;
    __syncthreads();
    if (threadIdx.x == 0) {
        double b = 0.0;
        int nwaves = (blockDim.x + 63) >> 6;
        for (int w = 0; w < nwaves; ++w) b += wsum[w];
        atomicAdd(acc, b);
    }
}

// ---------------- Kernel 4: finalize ----------------
__global__ void finalize_kernel(const double* __restrict__ acc, float* __restrict__ out) {
    out[0] = (float)acc[0];
}

static inline size_t align16(size_t x) { return (x + 15) & ~(size_t)15; }

extern "C" void kernel_launch(void* const* d_in, const int* in_sizes, int n_in,
                              void* d_out, int out_size, void* d_ws, size_t ws_size,
                              hipStream_t stream) {
    const float* pos     = (const float*)d_in[0];
    const int*   numbers = (const int*)d_in[1];
    const int*   ei      = (const int*)d_in[2];
    const int*   ej      = (const int*)d_in[3];
    const float* rcov    = (const float*)d_in[4];
    const float* r4r2    = (const float*)d_in[5];
    const float* c6tab   = (const float*)d_in[6];
    const float* cn_ref  = (const float*)d_in[7];

    int n_atoms = in_sizes[1];
    int n_edges = in_sizes[2];

    char* ws = (char*)d_ws;
    size_t off = 0;
    float* cn = (float*)(ws + off);       off += align16((size_t)n_atoms * 4);
    double* acc = (double*)(ws + off);    size_t zero_bytes = off + 16; off += 16;
    float* W = (float*)(ws + off);        off += (size_t)n_atoms * 32;
    size_t small_needed = off;
    float* atomrec = (float*)(ws + off);  off += (size_t)n_atoms * 32;
    float* tabp = (float*)(ws + off);     off += align16((size_t)MAXZ * MAXZ * TPAD * 4);
    f4* edgerec = (f4*)(ws + off);        off += (size_t)n_edges * 16;
    size_t full_needed = off;

    hipMemsetAsync(d_ws, 0, zero_bytes, stream);

    const int block = 256;
    int egrid = (n_edges + block - 1) / block;
    int egrid4 = (n_edges + block * IPT - 1) / (block * IPT);
    int agrid = (n_atoms + block - 1) / block;
    int pgrid = ((MAXZ * MAXZ > n_atoms ? MAXZ * MAXZ : n_atoms) + block - 1) / block;

    if (ws_size >= full_needed && n_atoms <= 65535) {
        pack_kernel<<<pgrid, block, 0, stream>>>(pos, numbers, rcov, r4r2, c6tab,
                                                 atomrec, tabp, n_atoms);
        cn_pre_kernel<<<egrid4, block, 0, stream>>>(atomrec, ei, ej, cn, edgerec, n_edges);
        weights_kernel<<<agrid, block, 0, stream>>>(cn, numbers, cn_ref, W, n_atoms);
        energy_kernel<<<egrid4, block, 0, stream>>>(edgerec, (const f4*)W, tabp, acc, n_edges);
    } else if (ws_size >= small_needed) {
        cn_kernel_old<<<egrid, block, 0, stream>>>(pos, numbers, ei, ej, rcov, cn, n_edges);
        weights_kernel<<<agrid, block, 0, stream>>>(cn, numbers, cn_ref, W, n_atoms);
        energy_kernel_old<<<egrid, block, 0, stream>>>(pos, numbers, ei, ej, r4r2, c6tab,
                                                       (const f4*)W, acc, n_edges);
    }
    finalize_kernel<<<1, 1, 0, stream>>>(acc, (float*)d_out);
}

// Round 4
// 110.495 us; speedup vs baseline: 1.5487x; 1.0891x over previous
//
#include <hip/hip_runtime.h>
#include <hip/hip_fp16.h>
#include <math.h>

// D3 constants
#define K1C 16.0f
#define K2C (4.0f / 3.0f)
#define K3C 4.0f
#define A1C 0.4f
#define A2C 5.0f
#define S6C 1.0f
#define S8C 0.78f
#define CN_CUT 25.0f
#define DISP_CUT 50.0f
#define MAXZ 95
#define NREF 5
#define THS 32        // fp16 table panel stride in halves (64 bytes)

typedef float f4 __attribute__((ext_vector_type(4)));

__device__ __forceinline__ unsigned h2bits(__half2 h) {
    union { __half2 h; unsigned u; } c; c.h = h; return c.u;
}
__device__ __forceinline__ float2 bits2f2(unsigned u) {
    union { unsigned u; __half2 h; } c; c.u = u; return __half22float2(c.h);
}

// ---------------- Kernel 0: pack posrec + fp16 table ----------------
// posrec[a] = {x, y, z, rcov[za]}   (16B)
// tabh[p*32 + k] = fp16(c6tab[p*25 + k]), zero-padded to 32 halves (64B)
__global__ void pack_kernel(const float* __restrict__ pos,
                            const int* __restrict__ numbers,
                            const float* __restrict__ rcov,
                            const float* __restrict__ c6tab,
                            f4* __restrict__ posrec,
                            unsigned* __restrict__ tabh,   // as uints (2 halves each)
                            int n_atoms) {
    int t = blockIdx.x * blockDim.x + threadIdx.x;
    int stride = gridDim.x * blockDim.x;
    const int ntab = MAXZ * MAXZ;
    for (int p = t; p < ntab; p += stride) {
        const float* src = c6tab + (size_t)p * 25;
        float v[32];
#pragma unroll
        for (int k = 0; k < 25; ++k) v[k] = src[k];
#pragma unroll
        for (int k = 25; k < 32; ++k) v[k] = 0.0f;
        unsigned u[16];
#pragma unroll
        for (int k = 0; k < 16; ++k) u[k] = h2bits(__floats2half2_rn(v[2 * k], v[2 * k + 1]));
        uint4* dst = (uint4*)(tabh + (size_t)p * (THS / 2));
        uint4 d0 = { u[0], u[1], u[2], u[3] };
        uint4 d1 = { u[4], u[5], u[6], u[7] };
        uint4 d2 = { u[8], u[9], u[10], u[11] };
        uint4 d3 = { u[12], u[13], u[14], u[15] };
        dst[0] = d0; dst[1] = d1; dst[2] = d2; dst[3] = d3;
    }
    for (int a = t; a < n_atoms; a += stride) {
        int z = numbers[a];
        f4 r = { pos[3 * a + 0], pos[3 * a + 1], pos[3 * a + 2], rcov[z] };
        posrec[a] = r;
    }
}

// ---------------- Kernel 1: fused CN scatter-add + 8B edge record ----------------
// edgerec[e] = {bits(d), i | j<<16}; strided-slot layout for full coalescing
__global__ void cn_pre_kernel(const f4* __restrict__ posrec,
                              const int* __restrict__ ei,
                              const int* __restrict__ ej,
                              float* __restrict__ cn,
                              uint2* __restrict__ edgerec,
                              int n_edges) {
    int t = blockIdx.x * blockDim.x + threadIdx.x;
    int lane = threadIdx.x & 63;
    int gwave = t >> 6;
    int nwave = (gridDim.x * blockDim.x) >> 6;
    for (int wb = gwave * 256; wb < n_edges; wb += nwave * 256) {
        int e0 = wb + lane;
        int idx[4], jdx[4];
        bool ok[4];
        f4 pa[4], pb[4];
#pragma unroll
        for (int s = 0; s < 4; ++s) {
            int e = e0 + s * 64;
            ok[s] = (e < n_edges);
            idx[s] = ok[s] ? ei[e] : 0;
            jdx[s] = ok[s] ? ej[e] : 0;
        }
#pragma unroll
        for (int s = 0; s < 4; ++s) { pa[s] = posrec[idx[s]]; pb[s] = posrec[jdx[s]]; }
#pragma unroll
        for (int s = 0; s < 4; ++s) {
            int e = e0 + s * 64;
            float dx = pb[s].x - pa[s].x;
            float dy = pb[s].y - pa[s].y;
            float dz = pb[s].z - pa[s].z;
            float d = sqrtf(dx * dx + dy * dy + dz * dz + 1e-20f);
            if (ok[s]) {
                if (d < CN_CUT) {
                    float rr = pa[s].w + pb[s].w;
                    float x = K1C * (K2C * rr / d - 1.0f);
                    atomicAdd(&cn[idx[s]], 1.0f / (1.0f + expf(-x)));
                }
                uint2 r;
                r.x = __float_as_uint(d);
                r.y = (unsigned)idx[s] | ((unsigned)jdx[s] << 16);
                edgerec[e] = r;
            }
        }
    }
}

// ---------------- Kernel 2: per-atom weight record ----------------
// wrec[a] = {h2(w0,w1), h2(w2,w3), bits(r4r2[z]), z}; w4 = 1 - sum
__global__ void weights_kernel(const float* __restrict__ cn,
                               const int* __restrict__ numbers,
                               const float* __restrict__ cn_ref,
                               const float* __restrict__ r4r2,
                               uint4* __restrict__ wrec,
                               int n_atoms) {
    int stride = gridDim.x * blockDim.x;
    for (int a = blockIdx.x * blockDim.x + threadIdx.x; a < n_atoms; a += stride) {
        int z = numbers[a];
        float c = cn[a];
        float gw[NREF];
        float norm = 0.0f;
        float best = -INFINITY;
        int bi = 0;
#pragma unroll
        for (int m = 0; m < NREF; ++m) {
            float r = cn_ref[z * NREF + m];
            bool valid = (r >= 0.0f);
            float tt = c - r;
            float g = valid ? expf(-K3C * tt * tt) : 0.0f;
            gw[m] = g;
            norm += g;
            if (valid && r > best) { best = r; bi = m; }
        }
        float out[NREF];
        if (norm > 1e-30f) {
            float inv = 1.0f / norm;
#pragma unroll
            for (int m = 0; m < NREF; ++m) out[m] = gw[m] * inv;
        } else {
#pragma unroll
            for (int m = 0; m < NREF; ++m) out[m] = (m == bi) ? 1.0f : 0.0f;
        }
        uint4 r;
        r.x = h2bits(__floats2half2_rn(out[0], out[1]));
        r.y = h2bits(__floats2half2_rn(out[2], out[3]));
        r.z = __float_as_uint(r4r2[z]);
        r.w = (unsigned)z;
        wrec[a] = r;
    }
}

// ---------------- Kernel 3: pair energy + reduction ----------------
__global__ void energy_kernel(const uint2* __restrict__ edgerec,
                              const uint4* __restrict__ wrec,
                              const unsigned* __restrict__ tabh,
                              double* __restrict__ acc,
                              int n_edges) {
    double local = 0.0;
    int t = blockIdx.x * blockDim.x + threadIdx.x;
    int lane = threadIdx.x & 63;
    int gwave = t >> 6;
    int nwave = (gridDim.x * blockDim.x) >> 6;
    for (int wb = gwave * 256; wb < n_edges; wb += nwave * 256) {
        int e0 = wb + lane;
        uint2 rec[4];
        bool ok[4];
#pragma unroll
        for (int s = 0; s < 4; ++s) {
            int e = e0 + s * 64;
            ok[s] = (e < n_edges);
            uint2 dead = { __float_as_uint(1e30f), 0u };
            rec[s] = ok[s] ? edgerec[e] : dead;
        }
        uint4 wri[4], wrj[4];
#pragma unroll
        for (int s = 0; s < 4; ++s) {
            unsigned ij = rec[s].y;
            wri[s] = wrec[ij & 0xFFFFu];
            wrj[s] = wrec[ij >> 16];
        }
        uint4 t0[4], t1[4], t2[4];
        unsigned t3[4];
#pragma unroll
        for (int s = 0; s < 4; ++s) {
            int pidx = (int)wri[s].w * MAXZ + (int)wrj[s].w;
            const uint4* Tv = (const uint4*)(tabh + (size_t)pidx * (THS / 2));
            t0[s] = Tv[0];
            t1[s] = Tv[1];
            t2[s] = Tv[2];
            t3[s] = ((const unsigned*)Tv)[12];
        }
#pragma unroll
        for (int s = 0; s < 4; ++s) {
            float d = __uint_as_float(rec[s].x);
            if (d < DISP_CUT) {
                float wiv[NREF], wjv[NREF];
                float2 p;
                p = bits2f2(wri[s].x); wiv[0] = p.x; wiv[1] = p.y;
                p = bits2f2(wri[s].y); wiv[2] = p.x; wiv[3] = p.y;
                wiv[4] = 1.0f - (wiv[0] + wiv[1] + wiv[2] + wiv[3]);
                p = bits2f2(wrj[s].x); wjv[0] = p.x; wjv[1] = p.y;
                p = bits2f2(wrj[s].y); wjv[2] = p.x; wjv[3] = p.y;
                wjv[4] = 1.0f - (wjv[0] + wjv[1] + wjv[2] + wjv[3]);
                unsigned us[13] = { t0[s].x, t0[s].y, t0[s].z, t0[s].w,
                                    t1[s].x, t1[s].y, t1[s].z, t1[s].w,
                                    t2[s].x, t2[s].y, t2[s].z, t2[s].w, t3[s] };
                float tt[26];
#pragma unroll
                for (int k = 0; k < 13; ++k) {
                    float2 q = bits2f2(us[k]);
                    tt[2 * k] = q.x;
                    tt[2 * k + 1] = q.y;
                }
                float c6 = 0.0f;
#pragma unroll
                for (int a = 0; a < NREF; ++a) {
                    float sacc = 0.0f;
#pragma unroll
                    for (int b = 0; b < NREF; ++b) sacc += wjv[b] * tt[a * NREF + b];
                    c6 += wiv[a] * sacc;
                }
                float r4i = __uint_as_float(wri[s].z);
                float r4j = __uint_as_float(wrj[s].z);
                float qq = 3.0f * r4i * r4j;
                float c8 = c6 * qq;
                float f = A1C * sqrtf(qq) + A2C;
                float f2 = f * f;
                float f6 = f2 * f2 * f2;
                float f8 = f6 * f2;
                float d2 = d * d;
                float d6 = d2 * d2 * d2;
                float d8 = d6 * d2;
                float e_pair = -(S6C * c6 / (d6 + f6) + S8C * c8 / (d8 + f8));
                local += 0.5 * (double)e_pair;
            }
        }
    }
#pragma unroll
    for (int off = 32; off > 0; off >>= 1) local += __shfl_down(local, off, 64);
    __shared__ double wsum[8];
    int wave = threadIdx.x >> 6;
    if ((threadIdx.x & 63) == 0) wsum[wave] = local;
    __syncthreads();
    if (threadIdx.x == 0) {
        double b = 0.0;
        int nwaves = (blockDim.x + 63) >> 6;
        for (int w = 0; w < nwaves; ++w) b += wsum[w];
        atomicAdd(acc, b);
    }
}

// ---------------- Fallback (small ws or n_atoms > 65535) ----------------
__global__ void cn_kernel_old(const float* __restrict__ pos,
                              const int* __restrict__ numbers,
                              const int* __restrict__ ei,
                              const int* __restrict__ ej,
                              const float* __restrict__ rcov,
                              float* __restrict__ cn,
                              int n_edges) {
    int stride = gridDim.x * blockDim.x;
    for (int e = blockIdx.x * blockDim.x + threadIdx.x; e < n_edges; e += stride) {
        int i = ei[e];
        int j = ej[e];
        float dx = pos[3 * j + 0] - pos[3 * i + 0];
        float dy = pos[3 * j + 1] - pos[3 * i + 1];
        float dz = pos[3 * j + 2] - pos[3 * i + 2];
        float d = sqrtf(dx * dx + dy * dy + dz * dz + 1e-20f);
        if (d < CN_CUT) {
            float rr = rcov[numbers[i]] + rcov[numbers[j]];
            float x = K1C * (K2C * rr / d - 1.0f);
            atomicAdd(&cn[i], 1.0f / (1.0f + expf(-x)));
        }
    }
}

__global__ void energy_kernel_old(const float* __restrict__ pos,
                                  const int* __restrict__ ei,
                                  const int* __restrict__ ej,
                                  const float* __restrict__ c6tab,
                                  const uint4* __restrict__ wrec,
                                  double* __restrict__ acc,
                                  int n_edges) {
    double local = 0.0;
    int stride = gridDim.x * blockDim.x;
    for (int e = blockIdx.x * blockDim.x + threadIdx.x; e < n_edges; e += stride) {
        int i = ei[e];
        int j = ej[e];
        float dx = pos[3 * j + 0] - pos[3 * i + 0];
        float dy = pos[3 * j + 1] - pos[3 * i + 1];
        float dz = pos[3 * j + 2] - pos[3 * i + 2];
        float d = sqrtf(dx * dx + dy * dy + dz * dz + 1e-20f);
        if (d < DISP_CUT) {
            uint4 wi = wrec[i], wj = wrec[j];
            int zi = (int)wi.w, zj = (int)wj.w;
            const float* T = c6tab + ((size_t)(zi * MAXZ + zj)) * 25;
            float wiv[NREF], wjv[NREF];
            float2 p;
            p = bits2f2(wi.x); wiv[0] = p.x; wiv[1] = p.y;
            p = bits2f2(wi.y); wiv[2] = p.x; wiv[3] = p.y;
            wiv[4] = 1.0f - (wiv[0] + wiv[1] + wiv[2] + wiv[3]);
            p = bits2f2(wj.x); wjv[0] = p.x; wjv[1] = p.y;
            p = bits2f2(wj.y); wjv[2] = p.x; wjv[3] = p.y;
            wjv[4] = 1.0f - (wjv[0] + wjv[1] + wjv[2] + wjv[3]);
            float c6 = 0.0f;
#pragma unroll
            for (int a = 0; a < NREF; ++a) {
                float sacc = 0.0f;
#pragma unroll
                for (int b = 0; b < NREF; ++b) sacc += wjv[b] * T[a * NREF + b];
                c6 += wiv[a] * sacc;
            }
            float qq = 3.0f * __uint_as_float(wi.z) * __uint_as_float(wj.z);
            float c8 = c6 * qq;
            float f = A1C * sqrtf(qq) + A2C;
            float f2 = f * f;
            float f6 = f2 * f2 * f2;
            float f8 = f6 * f2;
            float d2 = d * d;
            float d6 = d2 * d2 * d2;
            float d8 = d6 * d2;
            float e_pair = -(S6C * c6 / (d6 + f6) + S8C * c8 / (d8 + f8));
            local += 0.5 * (double)e_pair;
        }
    }
#pragma unroll
    for (int off = 32; off > 0; off >>= 1) local += __shfl_down(local, off, 64);
    __shared__ double wsum[8];
    int wave = threadIdx.x >> 6;
    if ((threadIdx.x & 63) == 0) wsum[wave] = local;
    __syncthreads();
    if (threadIdx.x == 0) {
        double b = 0.0;
        int nwaves = (blockDim.x + 63) >> 6;
        for (int w = 0; w < nwaves; ++w) b += wsum[w];
        atomicAdd(acc, b);
    }
}

// ---------------- finalize ----------------
__global__ void finalize_kernel(const double* __restrict__ acc, float* __restrict__ out) {
    out[0] = (float)acc[0];
}

static inline size_t align16(size_t x) { return (x + 15) & ~(size_t)15; }

extern "C" void kernel_launch(void* const* d_in, const int* in_sizes, int n_in,
                              void* d_out, int out_size, void* d_ws, size_t ws_size,
                              hipStream_t stream) {
    const float* pos     = (const float*)d_in[0];
    const int*   numbers = (const int*)d_in[1];
    const int*   ei      = (const int*)d_in[2];
    const int*   ej      = (const int*)d_in[3];
    const float* rcov    = (const float*)d_in[4];
    const float* r4r2    = (const float*)d_in[5];
    const float* c6tab   = (const float*)d_in[6];
    const float* cn_ref  = (const float*)d_in[7];

    int n_atoms = in_sizes[1];
    int n_edges = in_sizes[2];

    char* ws = (char*)d_ws;
    size_t off = 0;
    float* cn = (float*)(ws + off);        off += align16((size_t)n_atoms * 4);
    double* acc = (double*)(ws + off);     size_t zero_bytes = off + 16; off += 16;
    uint4* wrec = (uint4*)(ws + off);      off += (size_t)n_atoms * 16;
    size_t small_needed = off;
    f4* posrec = (f4*)(ws + off);          off += (size_t)n_atoms * 16;
    unsigned* tabh = (unsigned*)(ws + off); off += align16((size_t)MAXZ * MAXZ * (THS / 2) * 4);
    uint2* edgerec = (uint2*)(ws + off);   off += (size_t)n_edges * 8;
    size_t full_needed = off;

    hipMemsetAsync(d_ws, 0, zero_bytes, stream);

    const int block = 256;
    int egrid = (n_edges + block - 1) / block;
    int egrid4 = (n_edges + block * 4 - 1) / (block * 4);
    int agrid = (n_atoms + block - 1) / block;
    int pgrid = ((MAXZ * MAXZ > n_atoms ? MAXZ * MAXZ : n_atoms) + block - 1) / block;

    if (ws_size >= full_needed && n_atoms <= 65535) {
        pack_kernel<<<pgrid, block, 0, stream>>>(pos, numbers, rcov, c6tab,
                                                 posrec, tabh, n_atoms);
        cn_pre_kernel<<<egrid4, block, 0, stream>>>(posrec, ei, ej, cn, edgerec, n_edges);
        weights_kernel<<<agrid, block, 0, stream>>>(cn, numbers, cn_ref, r4r2, wrec, n_atoms);
        energy_kernel<<<egrid4, block, 0, stream>>>(edgerec, wrec, tabh, acc, n_edges);
    } else if (ws_size >= small_needed) {
        cn_kernel_old<<<egrid, block, 0, stream>>>(pos, numbers, ei, ej, rcov, cn, n_edges);
        weights_kernel<<<agrid, block, 0, stream>>>(cn, numbers, cn_ref, r4r2, wrec, n_atoms);
        energy_kernel_old<<<egrid, block, 0, stream>>>(pos, ei, ej, c6tab, wrec, acc, n_edges);
    }
    finalize_kernel<<<1, 1, 0, stream>>>(acc, (float*)d_out);
}